// Round 4
// baseline (116.428 us; speedup 1.0000x reference)
//
#include <hip/hip_runtime.h>
#include <hip/hip_bf16.h>
#include <math.h>

#define SEQ 4096
#define HD  64
#define NBATCH 4

#define EM1   1.71828182845904523536f
#define INVD5 (1.0f/(4096.f + 5.f*EM1))
#define INVD4 (1.0f/(4096.f + 4.f*EM1))
#define INVD3 (1.0f/(4096.f + 3.f*EM1))

typedef __attribute__((ext_vector_type(8))) short short8;
typedef __attribute__((ext_vector_type(4))) short short4v;
typedef __attribute__((ext_vector_type(4))) float f32x4;

__device__ __forceinline__ f32x4 mfma16(short8 a, short8 b, f32x4 c) {
    return __builtin_amdgcn_mfma_f32_16x16x32_bf16(a, b, c, 0, 0, 0);
}

__device__ __forceinline__ short bfs(float x) {
    __hip_bfloat16 h = __float2bfloat16(x);
    return *(short*)&h;
}

__device__ __forceinline__ float sf(short s) {
    __hip_bfloat16 h;
    *(short*)&h = s;
    return __bfloat162float(h);
}

__device__ __forceinline__ short8 pack8(float4 a, float4 b) {
    short8 r;
    r[0] = bfs(a.x); r[1] = bfs(a.y); r[2] = bfs(a.z); r[3] = bfs(a.w);
    r[4] = bfs(b.x); r[5] = bfs(b.y); r[6] = bfs(b.z); r[7] = bfs(b.w);
    return r;
}

// pack8 with uniform scale applied before rounding
__device__ __forceinline__ short8 pack8s(float4 a, float4 b, float s) {
    short8 r;
    r[0] = bfs(a.x*s); r[1] = bfs(a.y*s); r[2] = bfs(a.z*s); r[3] = bfs(a.w*s);
    r[4] = bfs(b.x*s); r[5] = bfs(b.y*s); r[6] = bfs(b.z*s); r[7] = bfs(b.w*s);
    return r;
}

__device__ __forceinline__ float b2f(__hip_bfloat16 h) { return __bfloat162float(h); }

#define WSTR 72   // padded W row stride in elems: 144 B -> 16B-aligned, 2-way banks

// ---------------------------------------------------------------------------
// Kernel 1 (fused wpack+projm): 512 blocks x 256 thr (4 waves).
// Waves 0/1: Q+K for row-half 0/1.  Waves 2/3: V + halo for row-half 0/1.
// M / ktot / vtot accumulated via device-scope fp32 atomics (no Mpart,
// no redprep kernel).  Accumulators pre-zeroed by a 66 KB memset.
// ---------------------------------------------------------------------------
__global__ __launch_bounds__(256, 2) void projm_kernel(
    const float* __restrict__ feat,
    const float* __restrict__ Wq, const float* __restrict__ Wk,
    const float* __restrict__ Wv,
    const float* __restrict__ bq, const float* __restrict__ bk,
    const float* __restrict__ bv,
    __hip_bfloat16* __restrict__ qsb, float* __restrict__ MTf,
    float* __restrict__ ktotF, float* __restrict__ VtotF,
    float* __restrict__ kedge)
{
    __shared__ __hip_bfloat16 WbL[3 * 64 * WSTR];
    __shared__ __hip_bfloat16 kT[64 * 40];    // [h][t-local 0..31]
    __shared__ __hip_bfloat16 vT[64 * 40];    // [h][idx 0..35] = t0-2 .. t0+33
    __shared__ __hip_bfloat16 lvt[64 * 40];   // locv5^T [h][t-local 0..31]
    __shared__ float kred[2][64];
    __shared__ float vred[2][64];

    const int tid  = threadIdx.x;
    const int wv   = tid >> 6, lane = tid & 63;
    const int rh   = wv & 1;            // row-half (16 rows)
    const int grp  = wv >> 1;           // 0: q+k, 1: v+halo
    const int quad = lane >> 4, ln = lane & 15;
    const int R0 = blockIdx.x * 32;
    const int b  = R0 >> 12;
    const int t0 = R0 & (SEQ - 1);
    const int chunk = blockIdx.x & 127;

    // A-fragments for this wave's 16 rows (waves 2/3 duplicate 0/1 -> L1 hit)
    short8 af0, af1;
    {
        const float* fp = feat + (size_t)(R0 + rh * 16 + ln) * HD + quad * 8;
        af0 = pack8(*(const float4*)(fp),      *(const float4*)(fp + 4));
        af1 = pack8(*(const float4*)(fp + 32), *(const float4*)(fp + 36));
    }

    // halo A-fragments (grp1 only): wave2 -> rows t0-2,t0-1; wave3 -> t0+32,+33
    short8 hf0, hf1;
    const bool hflag = (rh == 0) ? (t0 > 0) : (t0 < SEQ - 32);
    if (grp == 1) {
        const int hrow = (rh == 0) ? (t0 - 2 + ln) : (t0 + 32 + ln);
        if (ln < 2 && hflag) {
            const float* fp = feat + ((size_t)(b << 12) + hrow) * HD + quad * 8;
            hf0 = pack8(*(const float4*)(fp),      *(const float4*)(fp + 4));
            hf1 = pack8(*(const float4*)(fp + 32), *(const float4*)(fp + 36));
        } else {
            #pragma unroll
            for (int j = 0; j < 8; ++j) { hf0[j] = 0; hf1[j] = 0; }
        }
    }

    // pack W into LDS (row-major [col][k], padded stride WSTR)
    {
        const int r = tid >> 2, c = (tid & 3) * 16;
        #pragma unroll
        for (int m = 0; m < 3; ++m) {
            const float* W = (m == 0) ? Wq : (m == 1) ? Wk : Wv;
            const float s = (m == 0) ? 0.125f : 1.f;
            const float* src = W + r * 64 + c;
            float4 a0 = *(const float4*)(src);
            float4 a1 = *(const float4*)(src + 4);
            float4 a2 = *(const float4*)(src + 8);
            float4 a3 = *(const float4*)(src + 12);
            a0.x*=s; a0.y*=s; a0.z*=s; a0.w*=s;
            a1.x*=s; a1.y*=s; a1.z*=s; a1.w*=s;
            a2.x*=s; a2.y*=s; a2.z*=s; a2.w*=s;
            a3.x*=s; a3.y*=s; a3.z*=s; a3.w*=s;
            __hip_bfloat16* dst = WbL + m * 64 * WSTR + r * WSTR + c;
            *(short8*)(dst)     = pack8(a0, a1);
            *(short8*)(dst + 8) = pack8(a2, a3);
        }
    }
    __syncthreads();

    if (grp == 0) {
        #pragma unroll
        for (int ct = 0; ct < 4; ++ct) {
            const int col = ct * 16 + ln;
            // ---- q ----
            {
                const __hip_bfloat16* wp = WbL + col * WSTR + quad * 8;
                short8 b0 = *(const short8*)(wp);
                short8 b1 = *(const short8*)(wp + 32);
                f32x4 c = {};
                c = mfma16(af0, b0, c);
                c = mfma16(af1, b1, c);
                const float bl = bq[col] * 0.125f;
                #pragma unroll
                for (int rr = 0; rr < 4; ++rr)
                    qsb[(size_t)(R0 + rh * 16 + quad * 4 + rr) * HD + col] =
                        __float2bfloat16(c[rr] + bl);
            }
            // ---- k ----
            {
                const __hip_bfloat16* wp = WbL + 64 * WSTR + col * WSTR + quad * 8;
                short8 b0 = *(const short8*)(wp);
                short8 b1 = *(const short8*)(wp + 32);
                f32x4 c = {};
                c = mfma16(af0, b0, c);
                c = mfma16(af1, b1, c);
                float tot = c[0] + c[1] + c[2] + c[3];
                tot += __shfl_xor(tot, 16);
                tot += __shfl_xor(tot, 32);
                if (quad == 0) kred[rh][col] = tot;
                const float bl = bk[col];
                #pragma unroll
                for (int rr = 0; rr < 4; ++rr)
                    kT[col * 40 + rh * 16 + quad * 4 + rr] =
                        __float2bfloat16(c[rr] + bl);
            }
        }
    } else {
        #pragma unroll
        for (int ct = 0; ct < 4; ++ct) {
            const int col = ct * 16 + ln;
            const __hip_bfloat16* wp = WbL + 2 * 64 * WSTR + col * WSTR + quad * 8;
            short8 b0 = *(const short8*)(wp);
            short8 b1 = *(const short8*)(wp + 32);
            f32x4 c = {};
            c = mfma16(af0, b0, c);
            c = mfma16(af1, b1, c);
            float tot = c[0] + c[1] + c[2] + c[3];
            tot += __shfl_xor(tot, 16);
            tot += __shfl_xor(tot, 32);
            if (quad == 0) vred[rh][col] = tot;
            const float bl = bv[col];
            #pragma unroll
            for (int rr = 0; rr < 4; ++rr)
                vT[col * 40 + 2 + rh * 16 + quad * 4 + rr] =
                    __float2bfloat16(c[rr] + bl);
            // halo rows (reuse b0/b1): C rows 0,1 = halo
            f32x4 hc = {};
            hc = mfma16(hf0, b0, hc);
            hc = mfma16(hf1, b1, hc);
            if (quad == 0) {
                const int base = (rh == 0) ? 0 : 34;
                vT[col * 40 + base]     = __float2bfloat16(hflag ? hc[0] + bl : 0.f);
                vT[col * 40 + base + 1] = __float2bfloat16(hflag ? hc[1] + bl : 0.f);
            }
        }
    }
    __syncthreads();

    // column-sum totals: one device-scope atomic per (block, h)
    if (tid < 64) {
        unsafeAtomicAdd(&ktotF[b * 64 + tid],
                        kred[0][tid] + kred[1][tid] + 32.f * bk[tid]);
        unsafeAtomicAdd(&VtotF[b * 64 + tid],
                        vred[0][tid] + vred[1][tid] + 32.f * bv[tid]);
    }

    // locv5^T: thread (h, seg) -> 8 t's; window idx tl..tl+4 == t-2..t+2
    {
        const int h = tid & 63;
        const int tb = (tid >> 6) * 8;
        short4v u0 = *(const short4v*)&vT[h * 40 + tb];
        short4v u1 = *(const short4v*)&vT[h * 40 + tb + 4];
        short4v u2 = *(const short4v*)&vT[h * 40 + tb + 8];
        float w[12];
        #pragma unroll
        for (int j = 0; j < 4; ++j) {
            w[j]     = sf(u0[j]);
            w[j + 4] = sf(u1[j]);
            w[j + 8] = sf(u2[j]);
        }
        #pragma unroll
        for (int i = 0; i < 8; ++i)
            lvt[h * 40 + tb + i] =
                __float2bfloat16(w[i] + w[i+1] + w[i+2] + w[i+3] + w[i+4]);
    }

    // export edge k rows for mktot closed form (256 thr -> 256 entries)
    if (chunk == 0) {
        const int t = tid >> 6, h = tid & 63;
        kedge[b * 512 + t * 64 + h] = b2f(kT[h * 40 + t]);
    } else if (chunk == 127) {
        const int t = tid >> 6, h = tid & 63;
        kedge[b * 512 + (4 + t) * 64 + h] = b2f(kT[h * 40 + 28 + t]);
    }
    __syncthreads();

    // GEMM: M_chunk[h1][h2] = sum_t k[t][h1]*locv5[t][h2], K=32, 4 MFMAs/wave
    // accumulate transposed into fp32 MTf[b][h2][h1] via atomics
    {
        float* mt = MTf + (size_t)b * 4096;
        short8 a = *(const short8*)&kT[(wv * 16 + ln) * 40 + quad * 8];
        #pragma unroll
        for (int ct = 0; ct < 4; ++ct) {
            short8 bb = *(const short8*)&lvt[(ct * 16 + ln) * 40 + quad * 8];
            f32x4 acc = {};
            acc = mfma16(a, bb, acc);
            #pragma unroll
            for (int rr = 0; rr < 4; ++rr)
                unsafeAtomicAdd(
                    &mt[(ct * 16 + ln) * 64 + wv * 16 + quad * 4 + rr], acc[rr]);
        }
    }
}

// ---------------------------------------------------------------------------
// Kernel 2: out = (Vtot + qs·Mmain + (qs·ktot)·VDs) / (4096 + qs·mktot).
// grid 1024 x 128 (2 waves: wave w handles ct = 2w, 2w+1; denom MFMAs dup'd).
// Per-block 64-thread prep recomputes mktot closed form into LDS; M
// B-fragments loaded from fp32 MTf, scaled by EM1*INVD5 at cvt time.
// ---------------------------------------------------------------------------
__global__ __launch_bounds__(128) void out_kernel(
    const __hip_bfloat16* __restrict__ qsb, const float* __restrict__ MTf,
    const float* __restrict__ ktotF, const float* __restrict__ VtotF,
    const float* __restrict__ kedge, float* __restrict__ out)
{
    __shared__ __align__(16) __hip_bfloat16 mkB[64];
    __shared__ __align__(16) __hip_bfloat16 ktB[64];
    __shared__ float vdL[64];
    __shared__ float vtL[64];

    const int tid = threadIdx.x;
    const int wv = tid >> 6, lane = tid & 63;
    const int quad = lane >> 4, ln = lane & 15;
    const int R0 = blockIdx.x * 16;
    const int b = R0 >> 12;

    // per-block prep: closed-form mktot / VDs from totals + edges
    if (tid < 64) {
        const int hh = tid;
        const float kt = ktotF[b * 64 + hh];
        const float vt = VtotF[b * 64 + hh];
        const float e0 = kedge[b * 512 + 0 * 64 + hh];
        const float e1 = kedge[b * 512 + 1 * 64 + hh];
        const float e2 = kedge[b * 512 + 2 * 64 + hh];
        const float e3 = kedge[b * 512 + 3 * 64 + hh];
        const float f0 = kedge[b * 512 + 4 * 64 + hh];
        const float f1 = kedge[b * 512 + 5 * 64 + hh];
        const float f2 = kedge[b * 512 + 6 * 64 + hh];
        const float f3 = kedge[b * 512 + 7 * 64 + hh];
        const float Sint = 5.f*kt - 4.f*e0 - 3.f*e1 - 2.f*e2 - e3
                         - f0 - 2.f*f1 - 3.f*f2 - 4.f*f3;
        const float SlocD = Sint * INVD5
                          + (e0+e1+e2 + f1+f2+f3) * INVD3
                          + (e0+e1+e2+e3 + f0+f1+f2+f3) * INVD4;
        const float mk = kt * (4092.f*INVD5 + 2.f*INVD4 + 2.f*INVD3) + EM1 * SlocD;
        mkB[hh] = __float2bfloat16(mk);
        ktB[hh] = __float2bfloat16(kt);
        vdL[hh] = INVD5 * vt;
        vtL[hh] = vt;
    }

    short8 qa0, qa1;
    {
        const __hip_bfloat16* qp = qsb + (size_t)(R0 + ln) * HD + quad * 8;
        qa0 = *(const short8*)qp;
        qa1 = *(const short8*)(qp + 32);
    }

    // M B-fragments from fp32 accumulator, scaled at cvt
    const float SC = EM1 * INVD5;
    const float* mtb = MTf + (size_t)b * 4096;
    f32x4 acc[2];
    #pragma unroll
    for (int i = 0; i < 2; ++i) {
        const int ct = wv * 2 + i;
        const float* mrow = mtb + (ct * 16 + ln) * 64;
        short8 b0 = pack8s(*(const float4*)(mrow + quad * 8),
                           *(const float4*)(mrow + quad * 8 + 4), SC);
        short8 b1 = pack8s(*(const float4*)(mrow + 32 + quad * 8),
                           *(const float4*)(mrow + 36 + quad * 8), SC);
        f32x4 c = {};
        c = mfma16(qa0, b0, c);
        c = mfma16(qa1, b1, c);
        acc[i] = c;
    }

    __syncthreads();

    // uniform-B fragments from LDS-prepped bf16 vectors
    short8 mk0 = *(const short8*)&mkB[quad * 8];
    short8 mk1 = *(const short8*)&mkB[32 + quad * 8];
    short8 kt0 = *(const short8*)&ktB[quad * 8];
    short8 kt1 = *(const short8*)&ktB[32 + quad * 8];

    f32x4 accd = {}, acck = {};
    accd = mfma16(qa0, mk0, accd);
    accd = mfma16(qa1, mk1, accd);     // den per row (lane-uniform)
    acck = mfma16(qa0, kt0, acck);
    acck = mfma16(qa1, kt1, acck);     // qs·ktot per row

    float vt[2], vd[2];
    #pragma unroll
    for (int i = 0; i < 2; ++i) {
        const int ct = wv * 2 + i;
        vt[i] = vtL[ct * 16 + ln];
        vd[i] = vdL[ct * 16 + ln];
    }

    float inv[4];
    #pragma unroll
    for (int r = 0; r < 4; ++r) inv[r] = 1.f / (4096.f + accd[r]);

    #pragma unroll
    for (int i = 0; i < 2; ++i)
        #pragma unroll
        for (int r = 0; r < 4; ++r)
            out[(size_t)(R0 + quad * 4 + r) * HD + (wv * 2 + i) * 16 + ln] =
                (vt[i] + acc[i][r] + acck[r] * vd[i]) * inv[r];
}

// ---------------------------------------------------------------------------
extern "C" void kernel_launch(void* const* d_in, const int* in_sizes, int n_in,
                              void* d_out, int out_size, void* d_ws, size_t ws_size,
                              hipStream_t stream)
{
    const float* feat = (const float*)d_in[0];
    const float* Wq = (const float*)d_in[1];
    const float* bq = (const float*)d_in[2];
    const float* Wk = (const float*)d_in[3];
    const float* bk = (const float*)d_in[4];
    const float* Wv = (const float*)d_in[5];
    const float* bv = (const float*)d_in[6];
    float* out = (float*)d_out;

    char* ws = (char*)d_ws;
    __hip_bfloat16* qsb   = (__hip_bfloat16*)(ws + 0);                   // 2 MB
    float*          MTf   = (float*)(ws + (2u << 20));                   // 64 KB
    float*          ktotF = (float*)(ws + (2u << 20) + 65536);           // 1 KB
    float*          VtotF = (float*)(ws + (2u << 20) + 66560);           // 1 KB
    float*          kedge = (float*)(ws + (2u << 20) + 67584);           // 8 KB

    // zero the fp32 accumulators (MTf + ktotF + VtotF = 66 KB contiguous)
    hipMemsetAsync(ws + (2u << 20), 0, 67584, stream);

    projm_kernel<<<dim3(512), dim3(256), 0, stream>>>(
        feat, Wq, Wk, Wv, bq, bk, bv, qsb, MTf, ktotF, VtotF, kedge);
    out_kernel<<<dim3(1024), dim3(128), 0, stream>>>(
        qsb, MTf, ktotF, VtotF, kedge, out);
}

// Round 5
// 83.029 us; speedup vs baseline: 1.4023x; 1.4023x over previous
//
#include <hip/hip_runtime.h>
#include <hip/hip_bf16.h>
#include <math.h>

#define SEQ 4096
#define HD  64
#define NBATCH 4

#define EM1   1.71828182845904523536f
#define INVD5 (1.0f/(4096.f + 5.f*EM1))
#define INVD4 (1.0f/(4096.f + 4.f*EM1))
#define INVD3 (1.0f/(4096.f + 3.f*EM1))

typedef __attribute__((ext_vector_type(8))) short short8;
typedef __attribute__((ext_vector_type(4))) short short4v;
typedef __attribute__((ext_vector_type(4))) float f32x4;

__device__ __forceinline__ f32x4 mfma16(short8 a, short8 b, f32x4 c) {
    return __builtin_amdgcn_mfma_f32_16x16x32_bf16(a, b, c, 0, 0, 0);
}

__device__ __forceinline__ short bfs(float x) {
    __hip_bfloat16 h = __float2bfloat16(x);
    return *(short*)&h;
}

__device__ __forceinline__ float sf(short s) {
    __hip_bfloat16 h;
    *(short*)&h = s;
    return __bfloat162float(h);
}

__device__ __forceinline__ short8 pack8(float4 a, float4 b) {
    short8 r;
    r[0] = bfs(a.x); r[1] = bfs(a.y); r[2] = bfs(a.z); r[3] = bfs(a.w);
    r[4] = bfs(b.x); r[5] = bfs(b.y); r[6] = bfs(b.z); r[7] = bfs(b.w);
    return r;
}

// pack8 with uniform scale applied before rounding (same rounding point as
// the old LDS W-pack: scale in fp32, then one bf16 round)
__device__ __forceinline__ short8 pack8s(float4 a, float4 b, float s) {
    short8 r;
    r[0] = bfs(a.x*s); r[1] = bfs(a.y*s); r[2] = bfs(a.z*s); r[3] = bfs(a.w*s);
    r[4] = bfs(b.x*s); r[5] = bfs(b.y*s); r[6] = bfs(b.z*s); r[7] = bfs(b.w*s);
    return r;
}

__device__ __forceinline__ float b2f(__hip_bfloat16 h) { return __bfloat162float(h); }

// ---------------------------------------------------------------------------
// Kernel 1: fused projection + M-chunk GEMM.  512 blocks x 256 thr (4 waves).
// Waves 0/1: Q+K for row-half 0/1.  Waves 2/3: V + halo for row-half 0/1.
// W B-fragments are loaded DIRECTLY from global fp32 (L2-hot 16 KB each) and
// packed in-register -- no LDS W staging.  LDS = 16.4 KB -> 4 blocks/CU
// (launch_bounds(256,4)), 16 waves/CU for latency hiding.
// ---------------------------------------------------------------------------
__global__ __launch_bounds__(256, 4) void projm_kernel(
    const float* __restrict__ feat,
    const float* __restrict__ Wq, const float* __restrict__ Wk,
    const float* __restrict__ Wv,
    const float* __restrict__ bq, const float* __restrict__ bk,
    const float* __restrict__ bv,
    __hip_bfloat16* __restrict__ qsb, float* __restrict__ kpart,
    float* __restrict__ vpart, __hip_bfloat16* __restrict__ Mpart,
    float* __restrict__ kedge)
{
    __shared__ __hip_bfloat16 kT[64 * 40];    // [h][t-local 0..31]
    __shared__ __hip_bfloat16 vT[64 * 40];    // [h][idx 0..35] = t0-2 .. t0+33
    __shared__ __hip_bfloat16 lvt[64 * 40];   // locv5^T [h][t-local 0..31]
    __shared__ float kred[2][64];
    __shared__ float vred[2][64];

    const int tid  = threadIdx.x;
    const int wv   = tid >> 6, lane = tid & 63;
    const int rh   = wv & 1;            // row-half (16 rows)
    const int grp  = wv >> 1;           // 0: q+k, 1: v+halo
    const int quad = lane >> 4, ln = lane & 15;
    const int R0 = blockIdx.x * 32;
    const int b  = R0 >> 12;
    const int t0 = R0 & (SEQ - 1);
    const int chunk = blockIdx.x & 127;

    // A-fragments for this wave's 16 rows (waves 2/3 duplicate 0/1 -> L1 hit)
    short8 af0, af1;
    {
        const float* fp = feat + (size_t)(R0 + rh * 16 + ln) * HD + quad * 8;
        af0 = pack8(*(const float4*)(fp),      *(const float4*)(fp + 4));
        af1 = pack8(*(const float4*)(fp + 32), *(const float4*)(fp + 36));
    }

    // halo A-fragments (grp1 only): wave2 -> rows t0-2,t0-1; wave3 -> t0+32,+33
    short8 hf0, hf1;
    const bool hflag = (rh == 0) ? (t0 > 0) : (t0 < SEQ - 32);
    if (grp == 1) {
        const int hrow = (rh == 0) ? (t0 - 2 + ln) : (t0 + 32 + ln);
        if (ln < 2 && hflag) {
            const float* fp = feat + ((size_t)(b << 12) + hrow) * HD + quad * 8;
            hf0 = pack8(*(const float4*)(fp),      *(const float4*)(fp + 4));
            hf1 = pack8(*(const float4*)(fp + 32), *(const float4*)(fp + 36));
        } else {
            #pragma unroll
            for (int j = 0; j < 8; ++j) { hf0[j] = 0; hf1[j] = 0; }
        }
    }

    if (grp == 0) {
        #pragma unroll
        for (int ct = 0; ct < 4; ++ct) {
            const int col = ct * 16 + ln;
            // ---- q ---- (W fragment direct from global, scaled 0.125)
            {
                const float* wp = Wq + col * 64 + quad * 8;
                short8 b0 = pack8s(*(const float4*)(wp),
                                   *(const float4*)(wp + 4), 0.125f);
                short8 b1 = pack8s(*(const float4*)(wp + 32),
                                   *(const float4*)(wp + 36), 0.125f);
                f32x4 c = {};
                c = mfma16(af0, b0, c);
                c = mfma16(af1, b1, c);
                const float bl = bq[col] * 0.125f;
                #pragma unroll
                for (int rr = 0; rr < 4; ++rr)
                    qsb[(size_t)(R0 + rh * 16 + quad * 4 + rr) * HD + col] =
                        __float2bfloat16(c[rr] + bl);
            }
            // ---- k ----
            {
                const float* wp = Wk + col * 64 + quad * 8;
                short8 b0 = pack8(*(const float4*)(wp),
                                  *(const float4*)(wp + 4));
                short8 b1 = pack8(*(const float4*)(wp + 32),
                                  *(const float4*)(wp + 36));
                f32x4 c = {};
                c = mfma16(af0, b0, c);
                c = mfma16(af1, b1, c);
                float tot = c[0] + c[1] + c[2] + c[3];
                tot += __shfl_xor(tot, 16);
                tot += __shfl_xor(tot, 32);
                if (quad == 0) kred[rh][col] = tot;
                const float bl = bk[col];
                #pragma unroll
                for (int rr = 0; rr < 4; ++rr)
                    kT[col * 40 + rh * 16 + quad * 4 + rr] =
                        __float2bfloat16(c[rr] + bl);
            }
        }
    } else {
        #pragma unroll
        for (int ct = 0; ct < 4; ++ct) {
            const int col = ct * 16 + ln;
            const float* wp = Wv + col * 64 + quad * 8;
            short8 b0 = pack8(*(const float4*)(wp), *(const float4*)(wp + 4));
            short8 b1 = pack8(*(const float4*)(wp + 32),
                              *(const float4*)(wp + 36));
            f32x4 c = {};
            c = mfma16(af0, b0, c);
            c = mfma16(af1, b1, c);
            float tot = c[0] + c[1] + c[2] + c[3];
            tot += __shfl_xor(tot, 16);
            tot += __shfl_xor(tot, 32);
            if (quad == 0) vred[rh][col] = tot;
            const float bl = bv[col];
            #pragma unroll
            for (int rr = 0; rr < 4; ++rr)
                vT[col * 40 + 2 + rh * 16 + quad * 4 + rr] =
                    __float2bfloat16(c[rr] + bl);
            // halo rows (reuse b0/b1): C rows 0,1 = halo
            f32x4 hc = {};
            hc = mfma16(hf0, b0, hc);
            hc = mfma16(hf1, b1, hc);
            if (quad == 0) {
                const int base = (rh == 0) ? 0 : 34;
                vT[col * 40 + base]     = __float2bfloat16(hflag ? hc[0] + bl : 0.f);
                vT[col * 40 + base + 1] = __float2bfloat16(hflag ? hc[1] + bl : 0.f);
            }
        }
    }
    __syncthreads();

    // column-sum partials (128 per batch)
    if (tid < 64) {
        kpart[(size_t)blockIdx.x * 64 + tid] =
            kred[0][tid] + kred[1][tid] + 32.f * bk[tid];
        vpart[(size_t)blockIdx.x * 64 + tid] =
            vred[0][tid] + vred[1][tid] + 32.f * bv[tid];
    }

    // locv5^T: thread (h, seg) -> 8 t's; window idx tl..tl+4 == t-2..t+2
    {
        const int h = tid & 63;
        const int tb = (tid >> 6) * 8;
        short4v u0 = *(const short4v*)&vT[h * 40 + tb];
        short4v u1 = *(const short4v*)&vT[h * 40 + tb + 4];
        short4v u2 = *(const short4v*)&vT[h * 40 + tb + 8];
        float w[12];
        #pragma unroll
        for (int j = 0; j < 4; ++j) {
            w[j]     = sf(u0[j]);
            w[j + 4] = sf(u1[j]);
            w[j + 8] = sf(u2[j]);
        }
        #pragma unroll
        for (int i = 0; i < 8; ++i)
            lvt[h * 40 + tb + i] =
                __float2bfloat16(w[i] + w[i+1] + w[i+2] + w[i+3] + w[i+4]);
    }

    // export edge k rows for mktot closed form (256 thr -> 256 entries)
    if (chunk == 0) {
        const int t = tid >> 6, h = tid & 63;
        kedge[b * 512 + t * 64 + h] = b2f(kT[h * 40 + t]);
    } else if (chunk == 127) {
        const int t = tid >> 6, h = tid & 63;
        kedge[b * 512 + (4 + t) * 64 + h] = b2f(kT[h * 40 + 28 + t]);
    }
    __syncthreads();

    // GEMM: M_chunk[h1][h2] = sum_t k[t][h1]*locv5[t][h2], K=32, 4 MFMAs/wave
    {
        __hip_bfloat16* mp = Mpart + (size_t)(b * 128 + chunk) * 4096;
        short8 a = *(const short8*)&kT[(wv * 16 + ln) * 40 + quad * 8];
        #pragma unroll
        for (int ct = 0; ct < 4; ++ct) {
            short8 bb = *(const short8*)&lvt[(ct * 16 + ln) * 40 + quad * 8];
            f32x4 acc = {};
            acc = mfma16(a, bb, acc);
            #pragma unroll
            for (int rr = 0; rr < 4; ++rr)
                mp[(wv * 16 + quad * 4 + rr) * 64 + ct * 16 + ln] =
                    __float2bfloat16(acc[rr]);
        }
    }
}

// ---------------------------------------------------------------------------
// Kernel 2: grid (33, B) x 256 thr.
// x<32: vectorized Mpart reduction -> MTm (short8 loads, 2-stage LDS reduce).
// x==32: prep — ktot/Vtot from partials, mktot closed form (kedge), VDs.
// ---------------------------------------------------------------------------
__global__ __launch_bounds__(256) void redprep_kernel(
    const __hip_bfloat16* __restrict__ Mpart, const float* __restrict__ kpart,
    const float* __restrict__ vpart, const float* __restrict__ kedge,
    __hip_bfloat16* __restrict__ MTm, float* __restrict__ mktotF,
    float* __restrict__ ktotF, float* __restrict__ VDs,
    float* __restrict__ VtotF)
{
    const int b = blockIdx.y, x = blockIdx.x;
    const int tid = threadIdx.x;

    if (x < 32) {
        __shared__ float part[16][132];   // padded: 2-way banks on rd & wr
        const int gl = tid >> 4;          // col-group in block (16 x 8 elems)
        const int s  = tid & 15;          // chunk-sixteenth
        const int e  = x * 128 + gl * 8;
        const __hip_bfloat16* src =
            Mpart + ((size_t)b * 128 + s * 8) * 4096 + e;
        float sum[8] = {0.f,0.f,0.f,0.f,0.f,0.f,0.f,0.f};
        #pragma unroll
        for (int c = 0; c < 8; ++c) {
            short8 v = *(const short8*)(src + (size_t)c * 4096);
            #pragma unroll
            for (int j = 0; j < 8; ++j) sum[j] += sf(v[j]);
        }
        #pragma unroll
        for (int j = 0; j < 8; ++j) part[s][gl * 8 + j] = sum[j];
        __syncthreads();
        if (tid < 128) {
            float t = 0.f;
            #pragma unroll
            for (int ss = 0; ss < 16; ++ss) t += part[ss][tid];
            const int e2 = x * 128 + tid;
            const int h1 = e2 >> 6, h2 = e2 & 63;
            MTm[(size_t)b * 4096 + h2 * 64 + h1] =
                __float2bfloat16((EM1 * INVD5) * t);
        }
        return;
    }

    // prep (x == 32)
    __shared__ float red[4][64];
    __shared__ float red2[4][64];
    const int g = tid >> 6, h2 = tid & 63;
    {
        float kp = 0.f, vp = 0.f;
        for (int j = 0; j < 32; ++j) {
            kp += kpart[(size_t)(b * 128 + g * 32 + j) * 64 + h2];
            vp += vpart[(size_t)(b * 128 + g * 32 + j) * 64 + h2];
        }
        red[g][h2] = kp;
        red2[g][h2] = vp;
    }
    __syncthreads();
    if (tid < 64) {
        const int hh = tid;
        const float kt = red[0][hh] + red[1][hh] + red[2][hh] + red[3][hh];
        const float vt = red2[0][hh] + red2[1][hh] + red2[2][hh] + red2[3][hh];
        const float e0 = kedge[b * 512 + 0 * 64 + hh];
        const float e1 = kedge[b * 512 + 1 * 64 + hh];
        const float e2 = kedge[b * 512 + 2 * 64 + hh];
        const float e3 = kedge[b * 512 + 3 * 64 + hh];
        const float f0 = kedge[b * 512 + 4 * 64 + hh];
        const float f1 = kedge[b * 512 + 5 * 64 + hh];
        const float f2 = kedge[b * 512 + 6 * 64 + hh];
        const float f3 = kedge[b * 512 + 7 * 64 + hh];
        const float Sint = 5.f*kt - 4.f*e0 - 3.f*e1 - 2.f*e2 - e3
                         - f0 - 2.f*f1 - 3.f*f2 - 4.f*f3;
        const float SlocD = Sint * INVD5
                          + (e0+e1+e2 + f1+f2+f3) * INVD3
                          + (e0+e1+e2+e3 + f0+f1+f2+f3) * INVD4;
        mktotF[b * 64 + hh] = kt * (4092.f*INVD5 + 2.f*INVD4 + 2.f*INVD3) + EM1 * SlocD;
        ktotF[b * 64 + hh]  = kt;
        VDs[b * 64 + hh]    = INVD5 * vt;
        VtotF[b * 64 + hh]  = vt;
    }
}

// ---------------------------------------------------------------------------
// Kernel 3: out = (Vtot + qs·Mmain + (qs·ktot)·VDs) / (4096 + qs·mktot).
// grid 1024 x 128 (2 waves: wave w handles ct = 2w, 2w+1; denom MFMAs dup'd).
// ---------------------------------------------------------------------------
__global__ __launch_bounds__(128) void out_kernel(
    const __hip_bfloat16* __restrict__ qsb, const __hip_bfloat16* __restrict__ MTm,
    const float* __restrict__ mktotF, const float* __restrict__ ktotF,
    const float* __restrict__ VDs, const float* __restrict__ VtotF,
    float* __restrict__ out)
{
    const int tid = threadIdx.x;
    const int wv = tid >> 6, lane = tid & 63;
    const int quad = lane >> 4, ln = lane & 15;
    const int R0 = blockIdx.x * 16;
    const int b = R0 >> 12;

    short8 qa0, qa1;
    {
        const __hip_bfloat16* qp = qsb + (size_t)(R0 + ln) * HD + quad * 8;
        qa0 = *(const short8*)qp;
        qa1 = *(const short8*)(qp + 32);
    }

    const __hip_bfloat16* mtb = MTm + (size_t)b * 4096;
    f32x4 acc[2];
    #pragma unroll
    for (int i = 0; i < 2; ++i) {
        const int ct = wv * 2 + i;
        short8 b0 = *(const short8*)(mtb + (ct * 16 + ln) * 64 + quad * 8);
        short8 b1 = *(const short8*)(mtb + (ct * 16 + ln) * 64 + 32 + quad * 8);
        f32x4 c = {};
        c = mfma16(qa0, b0, c);
        c = mfma16(qa1, b1, c);
        acc[i] = c;
    }

    // uniform-B fragments: every lane holds the same vector slice
    short8 mk0, mk1, kt0, kt1;
    #pragma unroll
    for (int j = 0; j < 8; ++j) {
        mk0[j] = bfs(mktotF[b * 64 + quad * 8 + j]);
        mk1[j] = bfs(mktotF[b * 64 + 32 + quad * 8 + j]);
        kt0[j] = bfs(ktotF[b * 64 + quad * 8 + j]);
        kt1[j] = bfs(ktotF[b * 64 + 32 + quad * 8 + j]);
    }
    f32x4 accd = {}, acck = {};
    accd = mfma16(qa0, mk0, accd);
    accd = mfma16(qa1, mk1, accd);     // den per row (lane-uniform)
    acck = mfma16(qa0, kt0, acck);
    acck = mfma16(qa1, kt1, acck);     // qs·ktot per row

    float vt[2], vd[2];
    #pragma unroll
    for (int i = 0; i < 2; ++i) {
        const int ct = wv * 2 + i;
        vt[i] = VtotF[b * 64 + ct * 16 + ln];
        vd[i] = VDs[b * 64 + ct * 16 + ln];
    }

    float inv[4];
    #pragma unroll
    for (int r = 0; r < 4; ++r) inv[r] = 1.f / (4096.f + accd[r]);

    #pragma unroll
    for (int i = 0; i < 2; ++i)
        #pragma unroll
        for (int r = 0; r < 4; ++r)
            out[(size_t)(R0 + quad * 4 + r) * HD + (wv * 2 + i) * 16 + ln] =
                (vt[i] + acc[i][r] + acck[r] * vd[i]) * inv[r];
}

// ---------------------------------------------------------------------------
extern "C" void kernel_launch(void* const* d_in, const int* in_sizes, int n_in,
                              void* d_out, int out_size, void* d_ws, size_t ws_size,
                              hipStream_t stream)
{
    const float* feat = (const float*)d_in[0];
    const float* Wq = (const float*)d_in[1];
    const float* bq = (const float*)d_in[2];
    const float* Wk = (const float*)d_in[3];
    const float* bk = (const float*)d_in[4];
    const float* Wv = (const float*)d_in[5];
    const float* bv = (const float*)d_in[6];
    float* out = (float*)d_out;

    char* ws = (char*)d_ws;
    __hip_bfloat16* qsb    = (__hip_bfloat16*)(ws + 0);                  // 2 MB
    __hip_bfloat16* Mpart  = (__hip_bfloat16*)(ws + (2u << 20));         // 4 MB
    float*          kpart  = (float*)(ws + (6u << 20));                  // 128 KB
    float*          vpart  = (float*)(ws + (6u << 20) + 131072);         // 128 KB
    float*          kedge  = (float*)(ws + (6u << 20) + 262144);         // 8 KB
    __hip_bfloat16* MTm    = (__hip_bfloat16*)(ws + (6u << 20) + 270336);// 32 KB
    float*          mktotF = (float*)(ws + (6u << 20) + 303104);         // 1 KB
    float*          ktotF  = (float*)(ws + (6u << 20) + 304128);         // 1 KB
    float*          VDs    = (float*)(ws + (6u << 20) + 305152);         // 1 KB
    float*          VtotF  = (float*)(ws + (6u << 20) + 306176);         // 1 KB

    projm_kernel<<<dim3(512), dim3(256), 0, stream>>>(
        feat, Wq, Wk, Wv, bq, bk, bv, qsb, kpart, vpart, Mpart, kedge);
    redprep_kernel<<<dim3(33, NBATCH), dim3(256), 0, stream>>>(
        Mpart, kpart, vpart, kedge, MTm, mktotF, ktotF, VDs, VtotF);
    out_kernel<<<dim3(1024), dim3(128), 0, stream>>>(
        qsb, MTm, mktotF, ktotF, VDs, VtotF, out);
}

// Round 6
// 79.418 us; speedup vs baseline: 1.4660x; 1.0455x over previous
//
#include <hip/hip_runtime.h>
#include <hip/hip_bf16.h>
#include <math.h>

#define SEQ 4096
#define HD  64
#define NBATCH 4

#define EM1   1.71828182845904523536f
#define INVD5 (1.0f/(4096.f + 5.f*EM1))
#define INVD4 (1.0f/(4096.f + 4.f*EM1))
#define INVD3 (1.0f/(4096.f + 3.f*EM1))

typedef __attribute__((ext_vector_type(8))) short short8;
typedef __attribute__((ext_vector_type(4))) short short4v;
typedef __attribute__((ext_vector_type(4))) float f32x4;

__device__ __forceinline__ f32x4 mfma16(short8 a, short8 b, f32x4 c) {
    return __builtin_amdgcn_mfma_f32_16x16x32_bf16(a, b, c, 0, 0, 0);
}

__device__ __forceinline__ short bfs(float x) {
    __hip_bfloat16 h = __float2bfloat16(x);
    return *(short*)&h;
}

__device__ __forceinline__ float sf(short s) {
    __hip_bfloat16 h;
    *(short*)&h = s;
    return __bfloat162float(h);
}

__device__ __forceinline__ short8 pack8(float4 a, float4 b) {
    short8 r;
    r[0] = bfs(a.x); r[1] = bfs(a.y); r[2] = bfs(a.z); r[3] = bfs(a.w);
    r[4] = bfs(b.x); r[5] = bfs(b.y); r[6] = bfs(b.z); r[7] = bfs(b.w);
    return r;
}

__device__ __forceinline__ float b2f(__hip_bfloat16 h) { return __bfloat162float(h); }

#define WSTR 72   // padded W row stride in elems: 144 B -> 16B-aligned, 2-way banks

// ---------------------------------------------------------------------------
// Kernel 1: fused wpack+projm.  512 blocks x 512 thr (8 waves, one ROLE each):
//   wave = role*2 + rh,  role 0=q, 1=k, 2=v, 3=v-halo,  rh = row-half.
// Critical path per wave: 8 MFMA + one epilogue (r1 had 16 MFMA + two).
// Grid fully co-resident (1 block/CU); downstream kernels identical to r1.
// ---------------------------------------------------------------------------
__global__ __launch_bounds__(512, 4) void projm_kernel(
    const float* __restrict__ feat,
    const float* __restrict__ Wq, const float* __restrict__ Wk,
    const float* __restrict__ Wv,
    const float* __restrict__ bq, const float* __restrict__ bk,
    const float* __restrict__ bv,
    __hip_bfloat16* __restrict__ qsb, float* __restrict__ kpart,
    float* __restrict__ vpart, __hip_bfloat16* __restrict__ Mpart,
    float* __restrict__ kedge)
{
    __shared__ __hip_bfloat16 WbL[3 * 64 * WSTR];
    __shared__ __hip_bfloat16 kT[64 * 40];    // [h][t-local 0..31]
    __shared__ __hip_bfloat16 vT[64 * 40];    // [h][idx 0..35] = t0-2 .. t0+33
    __shared__ __hip_bfloat16 lvt[64 * 40];   // locv5^T [h][t-local 0..31]
    __shared__ float kred[2][64];
    __shared__ float vred[2][64];

    const int tid  = threadIdx.x;
    const int wv   = tid >> 6, lane = tid & 63;
    const int rh   = wv & 1;            // row-half (16 rows)
    const int role = wv >> 1;           // 0:q 1:k 2:v 3:halo
    const int quad = lane >> 4, ln = lane & 15;
    const int R0 = blockIdx.x * 32;
    const int b  = R0 >> 12;
    const int t0 = R0 & (SEQ - 1);
    const int chunk = blockIdx.x & 127;

    // A-fragments: roles 0-2 load this rh's 16 main rows (3x duplicate -> L1
    // hit); role 3 loads halo rows (lanes 0,1 only).
    short8 af0, af1;
    const bool hflag = (rh == 0) ? (t0 > 0) : (t0 < SEQ - 32);
    if (role < 3) {
        const float* fp = feat + (size_t)(R0 + rh * 16 + ln) * HD + quad * 8;
        af0 = pack8(*(const float4*)(fp),      *(const float4*)(fp + 4));
        af1 = pack8(*(const float4*)(fp + 32), *(const float4*)(fp + 36));
    } else {
        const int hrow = (rh == 0) ? (t0 - 2 + ln) : (t0 + 32 + ln);
        if (ln < 2 && hflag) {
            const float* fp = feat + ((size_t)(b << 12) + hrow) * HD + quad * 8;
            af0 = pack8(*(const float4*)(fp),      *(const float4*)(fp + 4));
            af1 = pack8(*(const float4*)(fp + 32), *(const float4*)(fp + 36));
        } else {
            #pragma unroll
            for (int j = 0; j < 8; ++j) { af0[j] = 0; af1[j] = 0; }
        }
    }

    // pack W into LDS (row-major [col][k], padded stride WSTR); 512 threads
    // -> 8 floats each per matrix
    {
        const int r = tid >> 3, c = (tid & 7) * 8;
        #pragma unroll
        for (int m = 0; m < 3; ++m) {
            const float* W = (m == 0) ? Wq : (m == 1) ? Wk : Wv;
            const float s = (m == 0) ? 0.125f : 1.f;
            const float* src = W + r * 64 + c;
            float4 a0 = *(const float4*)(src);
            float4 a1 = *(const float4*)(src + 4);
            a0.x*=s; a0.y*=s; a0.z*=s; a0.w*=s;
            a1.x*=s; a1.y*=s; a1.z*=s; a1.w*=s;
            *(short8*)(WbL + m * 64 * WSTR + r * WSTR + c) = pack8(a0, a1);
        }
    }
    __syncthreads();

    if (role == 0) {
        // ---- q ----
        #pragma unroll
        for (int ct = 0; ct < 4; ++ct) {
            const int col = ct * 16 + ln;
            const __hip_bfloat16* wp = WbL + col * WSTR + quad * 8;
            short8 b0 = *(const short8*)(wp);
            short8 b1 = *(const short8*)(wp + 32);
            f32x4 c = {};
            c = mfma16(af0, b0, c);
            c = mfma16(af1, b1, c);
            const float bl = bq[col] * 0.125f;
            #pragma unroll
            for (int rr = 0; rr < 4; ++rr)
                qsb[(size_t)(R0 + rh * 16 + quad * 4 + rr) * HD + col] =
                    __float2bfloat16(c[rr] + bl);
        }
    } else if (role == 1) {
        // ---- k ----
        #pragma unroll
        for (int ct = 0; ct < 4; ++ct) {
            const int col = ct * 16 + ln;
            const __hip_bfloat16* wp = WbL + 64 * WSTR + col * WSTR + quad * 8;
            short8 b0 = *(const short8*)(wp);
            short8 b1 = *(const short8*)(wp + 32);
            f32x4 c = {};
            c = mfma16(af0, b0, c);
            c = mfma16(af1, b1, c);
            float tot = c[0] + c[1] + c[2] + c[3];
            tot += __shfl_xor(tot, 16);
            tot += __shfl_xor(tot, 32);
            if (quad == 0) kred[rh][col] = tot;
            const float bl = bk[col];
            #pragma unroll
            for (int rr = 0; rr < 4; ++rr)
                kT[col * 40 + rh * 16 + quad * 4 + rr] =
                    __float2bfloat16(c[rr] + bl);
        }
    } else if (role == 2) {
        // ---- v (main rows) ----
        #pragma unroll
        for (int ct = 0; ct < 4; ++ct) {
            const int col = ct * 16 + ln;
            const __hip_bfloat16* wp = WbL + 2 * 64 * WSTR + col * WSTR + quad * 8;
            short8 b0 = *(const short8*)(wp);
            short8 b1 = *(const short8*)(wp + 32);
            f32x4 c = {};
            c = mfma16(af0, b0, c);
            c = mfma16(af1, b1, c);
            float tot = c[0] + c[1] + c[2] + c[3];
            tot += __shfl_xor(tot, 16);
            tot += __shfl_xor(tot, 32);
            if (quad == 0) vred[rh][col] = tot;
            const float bl = bv[col];
            #pragma unroll
            for (int rr = 0; rr < 4; ++rr)
                vT[col * 40 + 2 + rh * 16 + quad * 4 + rr] =
                    __float2bfloat16(c[rr] + bl);
        }
    } else {
        // ---- v halo rows: rh0 -> t0-2,t0-1 (idx 0,1); rh1 -> t0+32,+33 (34,35)
        #pragma unroll
        for (int ct = 0; ct < 4; ++ct) {
            const int col = ct * 16 + ln;
            const __hip_bfloat16* wp = WbL + 2 * 64 * WSTR + col * WSTR + quad * 8;
            short8 b0 = *(const short8*)(wp);
            short8 b1 = *(const short8*)(wp + 32);
            f32x4 hc = {};
            hc = mfma16(af0, b0, hc);
            hc = mfma16(af1, b1, hc);
            if (quad == 0) {
                const float bl = bv[col];
                const int base = (rh == 0) ? 0 : 34;
                vT[col * 40 + base]     = __float2bfloat16(hflag ? hc[0] + bl : 0.f);
                vT[col * 40 + base + 1] = __float2bfloat16(hflag ? hc[1] + bl : 0.f);
            }
        }
    }
    __syncthreads();

    // column-sum partials (128 per batch)
    if (tid < 64) {
        kpart[(size_t)blockIdx.x * 64 + tid] =
            kred[0][tid] + kred[1][tid] + 32.f * bk[tid];
        vpart[(size_t)blockIdx.x * 64 + tid] =
            vred[0][tid] + vred[1][tid] + 32.f * bv[tid];
    }

    // locv5^T: thread (h, seg) -> 4 t's; window idx tl..tl+4 == t-2..t+2
    {
        const int h = tid & 63;
        const int tb = (tid >> 6) * 4;
        short4v u0 = *(const short4v*)&vT[h * 40 + tb];
        short4v u1 = *(const short4v*)&vT[h * 40 + tb + 4];
        float w[8];
        #pragma unroll
        for (int j = 0; j < 4; ++j) {
            w[j]     = sf(u0[j]);
            w[j + 4] = sf(u1[j]);
        }
        #pragma unroll
        for (int i = 0; i < 4; ++i)
            lvt[h * 40 + tb + i] =
                __float2bfloat16(w[i] + w[i+1] + w[i+2] + w[i+3] + w[i+4]);
    }

    // export edge k rows for mktot closed form (first 256 thr -> 256 entries)
    if (chunk == 0) {
        if (tid < 256) {
            const int t = tid >> 6, h = tid & 63;
            kedge[b * 512 + t * 64 + h] = b2f(kT[h * 40 + t]);
        }
    } else if (chunk == 127) {
        if (tid < 256) {
            const int t = tid >> 6, h = tid & 63;
            kedge[b * 512 + (4 + t) * 64 + h] = b2f(kT[h * 40 + 28 + t]);
        }
    }
    __syncthreads();

    // GEMM: M_chunk[h1][h2] = sum_t k[t][h1]*locv5[t][h2], K=32.
    // 16 output tiles / 8 waves = 2 MFMA per wave.
    {
        __hip_bfloat16* mp = Mpart + (size_t)(b * 128 + chunk) * 4096;
        const int strip = wv >> 1;          // h1-strip 0..3
        const int cth   = wv & 1;           // ct-half
        short8 a = *(const short8*)&kT[(strip * 16 + ln) * 40 + quad * 8];
        #pragma unroll
        for (int i = 0; i < 2; ++i) {
            const int ct = cth * 2 + i;
            short8 bb = *(const short8*)&lvt[(ct * 16 + ln) * 40 + quad * 8];
            f32x4 acc = {};
            acc = mfma16(a, bb, acc);
            #pragma unroll
            for (int rr = 0; rr < 4; ++rr)
                mp[(strip * 16 + quad * 4 + rr) * 64 + ct * 16 + ln] =
                    __float2bfloat16(acc[rr]);
        }
    }
}

// ---------------------------------------------------------------------------
// Kernel 2: grid (33, B) x 256 thr.
// x<32: vectorized Mpart reduction -> MTm (short8 loads, 2-stage LDS reduce).
// x==32: prep — ktot/Vtot from partials, mktot closed form (kedge), VDs.
// ---------------------------------------------------------------------------
__global__ __launch_bounds__(256) void redprep_kernel(
    const __hip_bfloat16* __restrict__ Mpart, const float* __restrict__ kpart,
    const float* __restrict__ vpart, const float* __restrict__ kedge,
    __hip_bfloat16* __restrict__ MTm, float* __restrict__ mktotF,
    float* __restrict__ ktotF, float* __restrict__ VDs,
    float* __restrict__ VtotF)
{
    const int b = blockIdx.y, x = blockIdx.x;
    const int tid = threadIdx.x;

    if (x < 32) {
        __shared__ float part[16][132];   // padded: 2-way banks on rd & wr
        const int gl = tid >> 4;          // col-group in block (16 x 8 elems)
        const int s  = tid & 15;          // chunk-sixteenth
        const int e  = x * 128 + gl * 8;
        const __hip_bfloat16* src =
            Mpart + ((size_t)b * 128 + s * 8) * 4096 + e;
        float sum[8] = {0.f,0.f,0.f,0.f,0.f,0.f,0.f,0.f};
        #pragma unroll
        for (int c = 0; c < 8; ++c) {
            short8 v = *(const short8*)(src + (size_t)c * 4096);
            #pragma unroll
            for (int j = 0; j < 8; ++j) sum[j] += sf(v[j]);
        }
        #pragma unroll
        for (int j = 0; j < 8; ++j) part[s][gl * 8 + j] = sum[j];
        __syncthreads();
        if (tid < 128) {
            float t = 0.f;
            #pragma unroll
            for (int ss = 0; ss < 16; ++ss) t += part[ss][tid];
            const int e2 = x * 128 + tid;
            const int h1 = e2 >> 6, h2 = e2 & 63;
            MTm[(size_t)b * 4096 + h2 * 64 + h1] =
                __float2bfloat16((EM1 * INVD5) * t);
        }
        return;
    }

    // prep (x == 32)
    __shared__ float red[4][64];
    __shared__ float red2[4][64];
    const int g = tid >> 6, h2 = tid & 63;
    {
        float kp = 0.f, vp = 0.f;
        for (int j = 0; j < 32; ++j) {
            kp += kpart[(size_t)(b * 128 + g * 32 + j) * 64 + h2];
            vp += vpart[(size_t)(b * 128 + g * 32 + j) * 64 + h2];
        }
        red[g][h2] = kp;
        red2[g][h2] = vp;
    }
    __syncthreads();
    if (tid < 64) {
        const int hh = tid;
        const float kt = red[0][hh] + red[1][hh] + red[2][hh] + red[3][hh];
        const float vt = red2[0][hh] + red2[1][hh] + red2[2][hh] + red2[3][hh];
        const float e0 = kedge[b * 512 + 0 * 64 + hh];
        const float e1 = kedge[b * 512 + 1 * 64 + hh];
        const float e2 = kedge[b * 512 + 2 * 64 + hh];
        const float e3 = kedge[b * 512 + 3 * 64 + hh];
        const float f0 = kedge[b * 512 + 4 * 64 + hh];
        const float f1 = kedge[b * 512 + 5 * 64 + hh];
        const float f2 = kedge[b * 512 + 6 * 64 + hh];
        const float f3 = kedge[b * 512 + 7 * 64 + hh];
        const float Sint = 5.f*kt - 4.f*e0 - 3.f*e1 - 2.f*e2 - e3
                         - f0 - 2.f*f1 - 3.f*f2 - 4.f*f3;
        const float SlocD = Sint * INVD5
                          + (e0+e1+e2 + f1+f2+f3) * INVD3
                          + (e0+e1+e2+e3 + f0+f1+f2+f3) * INVD4;
        mktotF[b * 64 + hh] = kt * (4092.f*INVD5 + 2.f*INVD4 + 2.f*INVD3) + EM1 * SlocD;
        ktotF[b * 64 + hh]  = kt;
        VDs[b * 64 + hh]    = INVD5 * vt;
        VtotF[b * 64 + hh]  = vt;
    }
}

// ---------------------------------------------------------------------------
// Kernel 3: out = (Vtot + qs·Mmain + (qs·ktot)·VDs) / (4096 + qs·mktot).
// grid 1024 x 128 (2 waves: wave w handles ct = 2w, 2w+1; denom MFMAs dup'd).
// ---------------------------------------------------------------------------
__global__ __launch_bounds__(128) void out_kernel(
    const __hip_bfloat16* __restrict__ qsb, const __hip_bfloat16* __restrict__ MTm,
    const float* __restrict__ mktotF, const float* __restrict__ ktotF,
    const float* __restrict__ VDs, const float* __restrict__ VtotF,
    float* __restrict__ out)
{
    const int tid = threadIdx.x;
    const int wv = tid >> 6, lane = tid & 63;
    const int quad = lane >> 4, ln = lane & 15;
    const int R0 = blockIdx.x * 16;
    const int b = R0 >> 12;

    short8 qa0, qa1;
    {
        const __hip_bfloat16* qp = qsb + (size_t)(R0 + ln) * HD + quad * 8;
        qa0 = *(const short8*)qp;
        qa1 = *(const short8*)(qp + 32);
    }

    const __hip_bfloat16* mtb = MTm + (size_t)b * 4096;
    f32x4 acc[2];
    #pragma unroll
    for (int i = 0; i < 2; ++i) {
        const int ct = wv * 2 + i;
        short8 b0 = *(const short8*)(mtb + (ct * 16 + ln) * 64 + quad * 8);
        short8 b1 = *(const short8*)(mtb + (ct * 16 + ln) * 64 + 32 + quad * 8);
        f32x4 c = {};
        c = mfma16(qa0, b0, c);
        c = mfma16(qa1, b1, c);
        acc[i] = c;
    }

    // uniform-B fragments: every lane holds the same vector slice
    short8 mk0, mk1, kt0, kt1;
    #pragma unroll
    for (int j = 0; j < 8; ++j) {
        mk0[j] = bfs(mktotF[b * 64 + quad * 8 + j]);
        mk1[j] = bfs(mktotF[b * 64 + 32 + quad * 8 + j]);
        kt0[j] = bfs(ktotF[b * 64 + quad * 8 + j]);
        kt1[j] = bfs(ktotF[b * 64 + 32 + quad * 8 + j]);
    }
    f32x4 accd = {}, acck = {};
    accd = mfma16(qa0, mk0, accd);
    accd = mfma16(qa1, mk1, accd);     // den per row (lane-uniform)
    acck = mfma16(qa0, kt0, acck);
    acck = mfma16(qa1, kt1, acck);     // qs·ktot per row

    float vt[2], vd[2];
    #pragma unroll
    for (int i = 0; i < 2; ++i) {
        const int ct = wv * 2 + i;
        vt[i] = VtotF[b * 64 + ct * 16 + ln];
        vd[i] = VDs[b * 64 + ct * 16 + ln];
    }

    float inv[4];
    #pragma unroll
    for (int r = 0; r < 4; ++r) inv[r] = 1.f / (4096.f + accd[r]);

    #pragma unroll
    for (int i = 0; i < 2; ++i)
        #pragma unroll
        for (int r = 0; r < 4; ++r)
            out[(size_t)(R0 + quad * 4 + r) * HD + (wv * 2 + i) * 16 + ln] =
                (vt[i] + acc[i][r] + acck[r] * vd[i]) * inv[r];
}

// ---------------------------------------------------------------------------
extern "C" void kernel_launch(void* const* d_in, const int* in_sizes, int n_in,
                              void* d_out, int out_size, void* d_ws, size_t ws_size,
                              hipStream_t stream)
{
    const float* feat = (const float*)d_in[0];
    const float* Wq = (const float*)d_in[1];
    const float* bq = (const float*)d_in[2];
    const float* Wk = (const float*)d_in[3];
    const float* bk = (const float*)d_in[4];
    const float* Wv = (const float*)d_in[5];
    const float* bv = (const float*)d_in[6];
    float* out = (float*)d_out;

    char* ws = (char*)d_ws;
    __hip_bfloat16* qsb    = (__hip_bfloat16*)(ws + 0);                  // 2 MB
    __hip_bfloat16* Mpart  = (__hip_bfloat16*)(ws + (2u << 20));         // 4 MB
    float*          kpart  = (float*)(ws + (6u << 20));                  // 128 KB
    float*          vpart  = (float*)(ws + (6u << 20) + 131072);         // 128 KB
    float*          kedge  = (float*)(ws + (6u << 20) + 262144);         // 8 KB
    __hip_bfloat16* MTm    = (__hip_bfloat16*)(ws + (6u << 20) + 270336);// 32 KB
    float*          mktotF = (float*)(ws + (6u << 20) + 303104);         // 1 KB
    float*          ktotF  = (float*)(ws + (6u << 20) + 304128);         // 1 KB
    float*          VDs    = (float*)(ws + (6u << 20) + 305152);         // 1 KB
    float*          VtotF  = (float*)(ws + (6u << 20) + 306176);         // 1 KB

    projm_kernel<<<dim3(512), dim3(512), 0, stream>>>(
        feat, Wq, Wk, Wv, bq, bk, bv, qsb, kpart, vpart, Mpart, kedge);
    redprep_kernel<<<dim3(33, NBATCH), dim3(256), 0, stream>>>(
        Mpart, kpart, vpart, kedge, MTm, mktotF, ktotF, VDs, VtotF);
    out_kernel<<<dim3(1024), dim3(128), 0, stream>>>(
        qsb, MTm, mktotF, ktotF, VDs, VtotF, out);
}